// Round 26
// baseline (1056.214 us; speedup 1.0000x reference)
//
#include <hip/hip_runtime.h>
#include <cmath>

#define SEQ 2048
#define NB 64
#define VOC 128
#define DM 2176
#define NEG_INF -1e30f
#define GTLD 132   // padded leading dim for GT: bank = (4q+tk)&31, kills 8-way conflict

typedef __attribute__((ext_vector_type(8))) short short8;
typedef __attribute__((ext_vector_type(4))) float f32x4;
typedef __attribute__((ext_vector_type(4))) unsigned int uint4v;
typedef __attribute__((ext_vector_type(2))) unsigned int uint2v;

// ---------- bf16 split helpers (hi = truncation, lo = remainder) ----------
__device__ __forceinline__ void splitf(float x, unsigned short& h, unsigned short& l) {
    unsigned int u = __float_as_uint(x);
    h = (unsigned short)(u >> 16);
    float d = x - __uint_as_float(u & 0xFFFF0000u);
    l = (unsigned short)(__float_as_uint(d) >> 16);
}
__device__ __forceinline__ unsigned int bfpair(float x0, float x1, unsigned int& lopair) {
    unsigned int u0 = __float_as_uint(x0), u1 = __float_as_uint(x1);
    float d0 = x0 - __uint_as_float(u0 & 0xFFFF0000u);
    float d1 = x1 - __uint_as_float(u1 & 0xFFFF0000u);
    lopair = (__float_as_uint(d0) >> 16) | (__float_as_uint(d1) & 0xFFFF0000u);
    return (u0 >> 16) | (u1 & 0xFFFF0000u);
}

// ------------------------------------------------------------------
// Fused splits: blocks [0, n5) do 5-input plain split (pos, WQ1, WK1,
// WV1, emb; n* in f32x4 units); blocks [n5, n5+816) do the WK2|WV2|WQ2
// split+transpose -> W2T [384][2176] (flattened 68x12 grid).
// ------------------------------------------------------------------
__global__ __launch_bounds__(256) void split_all(
    const float* __restrict__ i0, unsigned short* __restrict__ h0, unsigned short* __restrict__ l0, int n0,
    const float* __restrict__ i1, unsigned short* __restrict__ h1, unsigned short* __restrict__ l1, int n1,
    const float* __restrict__ i2, unsigned short* __restrict__ h2, unsigned short* __restrict__ l2, int n2,
    const float* __restrict__ i3, unsigned short* __restrict__ h3, unsigned short* __restrict__ l3, int n3,
    const float* __restrict__ i4, unsigned short* __restrict__ h4, unsigned short* __restrict__ l4, int n4,
    int n5,
    const float* __restrict__ WK2, const float* __restrict__ WV2,
    const float* __restrict__ WQ2,
    unsigned short* __restrict__ w2h, unsigned short* __restrict__ w2l)
{
    __shared__ float tile[32][33];
    const int t = threadIdx.x;
    if ((int)blockIdx.x >= n5) {
        // ---- splitT3 path ----
        const int id2 = blockIdx.x - n5;
        const int bx = id2 % 68, by = id2 / 68;
        const int src = by >> 2, cblk = by & 3;
        const float* in = (src == 0) ? WK2 : (src == 1) ? WV2 : WQ2;
        const int r0 = bx * 32, c0 = cblk * 32;
        const int x = t & 31, y = t >> 5;
        #pragma unroll
        for (int i = 0; i < 4; ++i) {
            int r = y + i * 8;
            tile[r][x] = in[(size_t)(r0 + r) * 128 + c0 + x];
        }
        __syncthreads();
        #pragma unroll
        for (int i = 0; i < 4; ++i) {
            int c = y + i * 8;
            float v = tile[x][c];
            unsigned short h, l;
            splitf(v, h, l);
            size_t o = (size_t)(src * 128 + c0 + c) * 2176 + r0 + x;
            w2h[o] = h; w2l[o] = l;
        }
        return;
    }
    int i = blockIdx.x * 256 + t;
    const float* in; unsigned short *oh, *ol;
    if (i < n0) { in = i0; oh = h0; ol = l0; }
    else if ((i -= n0) < n1) { in = i1; oh = h1; ol = l1; }
    else if ((i -= n1) < n2) { in = i2; oh = h2; ol = l2; }
    else if ((i -= n2) < n3) { in = i3; oh = h3; ol = l3; }
    else if ((i -= n3) < n4) { in = i4; oh = h4; ol = l4; }
    else return;
    f32x4 v = *(const f32x4*)(in + (size_t)i * 4);
    unsigned int h01, h23, l01, l23;
    h01 = bfpair(v[0], v[1], l01);
    h23 = bfpair(v[2], v[3], l23);
    *(uint2v*)(oh + (size_t)i * 4) = (uint2v){h01, h23};
    *(uint2v*)(ol + (size_t)i * 4) = (uint2v){l01, l23};
}

// ------------------------------------------------------------------
// Quad-descriptor split-bf16 MFMA GEMM (NT), 3-term, plus optional
// trailing transpose region: blocks [nGemmTot, grid) split-transpose
// tsrc[row][0..tNC) (ld tld) -> (th,tl)[c][r] with out ld tNR.
// Tile 128x128, BK=64, 4 waves. mode bit0: f32 C; bit1: split Ch/Cl.
// tri: linear id -> lower-triangle (bm,bn) for bm<16 + full row bm=16.
// ------------------------------------------------------------------
struct GemmDesc {
    const unsigned short *Ah, *Al, *Bh, *Bl;
    float* C; unsigned short *Ch, *Cl;
    int lda, ldb, ldc, K, nx, mode, tri;
};

__global__ __launch_bounds__(256, 2) void gemm_nt_multi4t(
    GemmDesc d0, GemmDesc d1, GemmDesc d2, GemmDesc d3,
    int n0, int n01, int n012, int nGemmTot,
    const float* __restrict__ tsrc, int tld, int tNR, int tNC,
    unsigned short* __restrict__ th, unsigned short* __restrict__ tl)
{
    __shared__ __align__(16) unsigned short sAh[128 * 64], sAl[128 * 64];
    __shared__ __align__(16) unsigned short sBh[128 * 64], sBl[128 * 64];
    const int t = threadIdx.x;
    if ((int)blockIdx.x >= nGemmTot) {
        // ---- transpose path (splitT of tsrc) ----
        float* tile = (float*)sAh;            // 32x33 floats, reuse LDS
        const int id2 = blockIdx.x - nGemmTot;
        const int nbx = tNR >> 5;             // blocks along rows
        const int bx = id2 % nbx, by = id2 / nbx;
        const int r0 = bx * 32, c0 = by * 32;
        const int x = t & 31, y = t >> 5;
        #pragma unroll
        for (int i = 0; i < 4; ++i) {
            int r = y + i * 8;
            tile[r * 33 + x] = tsrc[(size_t)(r0 + r) * tld + c0 + x];
        }
        __syncthreads();
        #pragma unroll
        for (int i = 0; i < 4; ++i) {
            int c = y + i * 8;
            float v = tile[x * 33 + c];
            unsigned short h, l;
            splitf(v, h, l);
            size_t o = (size_t)(c0 + c) * tNR + r0 + x;
            th[o] = h; tl[o] = l;
        }
        return;
    }
    GemmDesc d;
    int id = blockIdx.x;
    if (id < n0) d = d0;
    else if (id < n01) { d = d1; id -= n0; }
    else if (id < n012) { d = d2; id -= n01; }
    else { d = d3; id -= n012; }
    int bmi, bni;
    if (d.tri) {
        if (id < 136) {
            int bm_ = (int)((sqrtf(8.f * id + 1.f) - 1.f) * 0.5f);
            while ((bm_ + 1) * (bm_ + 2) / 2 <= id) ++bm_;
            while (bm_ * (bm_ + 1) / 2 > id) --bm_;
            bmi = bm_; bni = id - bm_ * (bm_ + 1) / 2;
        } else { bmi = 16; bni = id - 136; }
    } else { bmi = id / d.nx; bni = id % d.nx; }
    const int bm = bmi * 128, bn = bni * 128;
    const int lane = t & 63, wave = t >> 6;
    const int wr = wave >> 1, wc = wave & 1;
    const int lr = lane & 15;

    f32x4 acc[4][4];
    #pragma unroll
    for (int i = 0; i < 4; ++i)
        #pragma unroll
        for (int j = 0; j < 4; ++j) acc[i][j] = (f32x4){0.f, 0.f, 0.f, 0.f};

    for (int k0 = 0; k0 < d.K; k0 += 64) {
        __syncthreads();
        #pragma unroll
        for (int i = 0; i < 4; ++i) {
            int idx = t + i * 256;
            int r = idx >> 3, kc = (idx & 7) * 8;
            int off = (r * 128 + kc * 2) ^ ((r & 7) << 4);
            size_t ga = (size_t)(bm + r) * d.lda + k0 + kc;
            size_t gb = (size_t)(bn + r) * d.ldb + k0 + kc;
            *(short8*)((char*)sAh + off) = *(const short8*)(d.Ah + ga);
            *(short8*)((char*)sAl + off) = *(const short8*)(d.Al + ga);
            *(short8*)((char*)sBh + off) = *(const short8*)(d.Bh + gb);
            *(short8*)((char*)sBl + off) = *(const short8*)(d.Bl + gb);
        }
        __syncthreads();
        #pragma unroll
        for (int ks = 0; ks < 2; ++ks) {
            const int kby = ks * 64 + ((lane >> 4) << 4);
            short8 ah[4], al[4];
            #pragma unroll
            for (int rf = 0; rf < 4; ++rf) {
                int row = wr * 64 + rf * 16 + lr;
                int off = (row * 128 + kby) ^ ((row & 7) << 4);
                ah[rf] = *(const short8*)((const char*)sAh + off);
                al[rf] = *(const short8*)((const char*)sAl + off);
            }
            #pragma unroll
            for (int cf = 0; cf < 4; ++cf) {
                int col = wc * 64 + cf * 16 + lr;
                int off = (col * 128 + kby) ^ ((col & 7) << 4);
                short8 bh = *(const short8*)((const char*)sBh + off);
                short8 bl = *(const short8*)((const char*)sBl + off);
                #pragma unroll
                for (int rf = 0; rf < 4; ++rf) {
                    acc[rf][cf] = __builtin_amdgcn_mfma_f32_16x16x32_bf16(ah[rf], bh, acc[rf][cf], 0, 0, 0);
                    acc[rf][cf] = __builtin_amdgcn_mfma_f32_16x16x32_bf16(ah[rf], bl, acc[rf][cf], 0, 0, 0);
                    acc[rf][cf] = __builtin_amdgcn_mfma_f32_16x16x32_bf16(al[rf], bh, acc[rf][cf], 0, 0, 0);
                }
            }
        }
    }
    #pragma unroll
    for (int rf = 0; rf < 4; ++rf) {
        #pragma unroll
        for (int j = 0; j < 4; ++j) {
            int row = bm + wr * 64 + rf * 16 + ((lane >> 4) << 2) + j;
            #pragma unroll
            for (int cf = 0; cf < 4; ++cf) {
                int col = bn + wc * 64 + cf * 16 + lr;
                float v = acc[rf][cf][j];
                size_t o = (size_t)row * d.ldc + col;
                if (d.mode & 1) d.C[o] = v;
                if (d.mode & 2) { unsigned short h, l; splitf(v, h, l); d.Ch[o] = h; d.Cl[o] = l; }
            }
        }
    }
}

// ------------------------------------------------------------------
// block reduce helpers
// ------------------------------------------------------------------
__device__ __forceinline__ float blk_reduce_max(float v, float* red, int t)
{
    red[t] = v; __syncthreads();
    #pragma unroll
    for (int s = 128; s >= 1; s >>= 1) {
        if (t < s) red[t] = fmaxf(red[t], red[t + s]);
        __syncthreads();
    }
    float r = red[0]; __syncthreads(); return r;
}
__device__ __forceinline__ float blk_reduce_sum(float v, float* red, int t)
{
    red[t] = v; __syncthreads();
    #pragma unroll
    for (int s = 128; s >= 1; s >>= 1) {
        if (t < s) red[t] += red[t + s];
        __syncthreads();
    }
    float r = red[0]; __syncthreads(); return r;
}

// ------------------------------------------------------------------
// MFMA attention core, v12: v11 (R25-proven, GTLD pad) with the 64
// merged stage-2 P1+P2 blocks moved to the FRONT of dispatch order
// (y < 8) so they run during the occupancy ramp instead of extending
// the kernel tail. Grid (8, 136), 256 threads:
//   y < 8   : merged stage-2 P1+P2 for batch y*8+x -> writes q2.
//   y >= 8  : attention. b = (y-8)>>1, sel = (y-8)&1.
//             sel 0 -> q-tiles {x, 31-x}; sel 1 -> {15-x, 16+x} (66 iters).
//             gridDim.x = 8 keeps linear%8 == x -> XCD-local G.
// ------------------------------------------------------------------
__global__ __launch_bounds__(256, 3) void attn_mfma(
    const int* __restrict__ tok,
    const float* __restrict__ G,
    const float* __restrict__ VpKVQ,
    const unsigned short* __restrict__ VpTh, const unsigned short* __restrict__ VpTl,
    const float* __restrict__ Tx, const float* __restrict__ plq,
    const float* __restrict__ beta1,
    float* __restrict__ O, float* __restrict__ q2)
{
    const int t = threadIdx.x;
    const int lane = t & 63, wave = t >> 6;
    const float c1 = beta1[0] * 1.12890625f;

    __shared__ __align__(16) unsigned short Ph[2][64 * 32], Pl[2][64 * 32];
    __shared__ float GT[64 * GTLD];
    __shared__ float m_s[64], l_s[64], rs_s[2][64];
    __shared__ int tq_s[64], tk_s[3][32];

    if (blockIdx.y < 8) {
        // ======== merged stage-2 P1+P2 for batch bb (dispatched first) ========
        const int bb = blockIdx.y * 8 + blockIdx.x;
        float* a_s = GT;              // [2048]
        float* red_s = GT + 2048;     // [256]
        float* w_s = GT + 2048 + 256; // [128]
        const int* tokb = tok + (size_t)bb * SEQ;
        const int tq = tokb[SEQ - 1];
        const float* Grow_q = G + (size_t)(SEQ - 1) * 2176;
        const float* Grow_t = G + (size_t)(2048 + tq) * 2176;

        float lmax = NEG_INF;
        for (int i = t; i < SEQ; i += 256) {
            int tk = tokb[i];
            float s = c1 * (Grow_t[2048 + tk] + Grow_t[i] + Grow_q[2048 + tk] + Grow_q[i]);
            a_s[i] = s;
            lmax = fmaxf(lmax, s);
        }
        float m = blk_reduce_max(lmax, red_s, t);
        float lsum = 0.f;
        for (int i = t; i < SEQ; i += 256) {
            float e = __expf(a_s[i] - m);
            a_s[i] = e;
            lsum += e;
        }
        float l = blk_reduce_sum(lsum, red_s, t);
        float inv = 1.f / l;
        if (t < VOC) w_s[t] = 0.f;
        __syncthreads();
        for (int i = t; i < SEQ; i += 256) {
            float a = a_s[i] * inv;
            a_s[i] = a;
            atomicAdd(&w_s[tokb[i]], a);
        }
        __syncthreads();
        // ---- P2: q2[bb][v] ----
        const int v = t & 127, half = t >> 7;
        float acc = 0.f;
        for (int i = 0; i < 1024; ++i) {
            int s = half * 1024 + i;
            acc += a_s[s] * VpKVQ[(size_t)s * 384 + 256 + v];
        }
        if (half == 0) {
            for (int tt = 0; tt < VOC; ++tt)
                acc += w_s[tt] * VpKVQ[(size_t)(2048 + tt) * 384 + 256 + v];
        }
        red_s[t] = acc; __syncthreads();
        if (t < VOC)
            q2[bb * VOC + t] = red_s[t] + red_s[t + 128] + Tx[tq * 384 + 256 + t] + plq[t];
        return;
    }

    // ======== attention path ========
    const int yy = blockIdx.y - 8;
    const int b = yy >> 1;
    const int sel = yy & 1;
    const int grp = blockIdx.x;      // 0..7, == XCD under linear round-robin

    const int qr = t >> 3;           // 0..31
    const int kb4 = (t & 7) * 4;     // 0..28
    const int lr = lane & 15;
    const int ksl = lane >> 4;       // 0..3
    const int kk0 = ksl * 8;
    const float* TvT = VpKVQ + (size_t)2048 * 384;   // token rows [128][384]

    const int qts[2] = {sel ? (15 - grp) : grp, sel ? (16 + grp) : (31 - grp)};

    for (int pass = 0; pass < 2; ++pass) {
        const int qt = qts[pass];
        const int q0 = qt * 64;
        const int niter = 2 * qt + 2;

        __syncthreads();                 // previous pass fully done
        if (t < 64) {
            tq_s[t] = tok[(size_t)b * SEQ + q0 + t];
            m_s[t] = NEG_INF;
            l_s[t] = 0.f;
        }
        __syncthreads();                 // tq_s visible
        // ---- GT[q][tk] = Gqt + Gtt (one coalesced pass) ----
        {
            const int c4 = (t & 31) * 4;
            #pragma unroll
            for (int i = 0; i < 8; ++i) {
                int q = (t >> 5) + i * 8;
                f32x4 a = *(const f32x4*)&G[(size_t)(q0 + q) * 2176 + 2048 + c4];
                f32x4 g = *(const f32x4*)&G[(size_t)(2048 + tq_s[q]) * 2176 + 2048 + c4];
                *(f32x4*)&GT[q * GTLD + c4] = a + g;
            }
        }
        // prologue: tokens tile0 -> slot 0, G rows tile0 -> regs
        if (t < 32) tk_s[0][t] = tok[(size_t)b * SEQ + t];
        f32x4 gqk_c[2], gtk_c[2];
        #pragma unroll
        for (int rr = 0; rr < 2; ++rr) {
            int q = qr + rr * 32;
            gqk_c[rr] = *(const f32x4*)&G[(size_t)(q0 + q) * 2176 + kb4];
            gtk_c[rr] = *(const f32x4*)&G[(size_t)(2048 + tq_s[q]) * 2176 + kb4];
        }

        f32x4 acc[4][4];
        #pragma unroll
        for (int i = 0; i < 4; ++i)
            #pragma unroll
            for (int j = 0; j < 4; ++j) acc[i][j] = (f32x4){0.f, 0.f, 0.f, 0.f};

        // SCORE(i): uses gqk_c/gtk_c (tile i), tk_s[i%3]; writes P[i&1],
        // rs_s[i&1]; prefetches tokens(i+1) -> slot (i+1)%3.
        auto SCORE = [&](int i) {
            const int k0s = i * 32;
            const int cs = i & 1;
            const int sl = i % 3;
            unsigned short* PhC = Ph[cs];
            unsigned short* PlC = Pl[cs];
            const int k0p = (i + 1 < niter) ? k0s + 32 : k0s;
            if (t < 32) tk_s[(i + 1) % 3][t] = tok[(size_t)b * SEQ + k0p + t];
            #pragma unroll
            for (int rr = 0; rr < 2; ++rr) {
                const int q = qr + rr * 32;
                const int qg = q0 + q;
                float s[4];
                #pragma unroll
                for (int j = 0; j < 4; ++j) {
                    int kg = k0s + kb4 + j;
                    s[j] = (kg <= qg)
                         ? c1 * (gqk_c[rr][j] + gtk_c[rr][j] + GT[q * GTLD + tk_s[sl][kb4 + j]])
                         : NEG_INF;
                }
                float tmax = fmaxf(fmaxf(s[0], s[1]), fmaxf(s[2], s[3]));
                tmax = fmaxf(tmax, __shfl_xor(tmax, 1));
                tmax = fmaxf(tmax, __shfl_xor(tmax, 2));
                tmax = fmaxf(tmax, __shfl_xor(tmax, 4));
                const float m_old = m_s[q];
                const float mnew = fmaxf(m_old, tmax);
                float p0 = __expf(s[0] - mnew), p1 = __expf(s[1] - mnew);
                float p2 = __expf(s[2] - mnew), p3 = __expf(s[3] - mnew);
                float lsum = p0 + p1 + p2 + p3;
                lsum += __shfl_xor(lsum, 1);
                lsum += __shfl_xor(lsum, 2);
                lsum += __shfl_xor(lsum, 4);
                unsigned int l01, l23;
                unsigned int h01 = bfpair(p0, p1, l01);
                unsigned int h23 = bfpair(p2, p3, l23);
                int i16 = q * 4 + (((kb4 >> 3) + (q >> 1)) & 3);
                int pbyte = i16 * 16 + ((kb4 & 4) << 1);
                *(uint2v*)((char*)PhC + pbyte) = (uint2v){h01, h23};
                *(uint2v*)((char*)PlC + pbyte) = (uint2v){l01, l23};
                if ((t & 7) == 0) {
                    float rs = __expf(m_old - mnew);
                    m_s[q] = mnew;
                    l_s[q] = l_s[q] * rs + lsum;
                    rs_s[cs][q] = rs;
                }
            }
        };

        // ---- score(0) ----
        __syncthreads();                 // GT + tk slot0 visible
        SCORE(0);
        __syncthreads();                 // barrier 0: P[0]/rs[0] visible

        for (int j = 0; j < niter; ++j) {
            const int cur = j & 1;
            const int sl = j % 3;
            const int k0 = j * 32;

            // ---- G-row prefetch for score(j+1) (regs; hides under PV) ----
            const int k0n = (j + 1 < niter) ? k0 + 32 : k0;
            #pragma unroll
            for (int rr = 0; rr < 2; ++rr) {
                int q = qr + rr * 32;
                gqk_c[rr] = *(const f32x4*)&G[(size_t)(q0 + q) * 2176 + k0n + kb4];
                gtk_c[rr] = *(const f32x4*)&G[(size_t)(2048 + tq_s[q]) * 2176 + k0n + kb4];
            }

            // ---- P frags + rescale ----
            const unsigned short* PhC = Ph[cur];
            const unsigned short* PlC = Pl[cur];
            short8 pah[4], pal[4];
            f32x4 rsv[4];
            #pragma unroll
            for (int qf = 0; qf < 4; ++qf) {
                int row = qf * 16 + lr;
                int i16 = row * 4 + ((ksl + (row >> 1)) & 3);
                pah[qf] = *(const short8*)((const char*)PhC + i16 * 16);
                pal[qf] = *(const short8*)((const char*)PlC + i16 * 16);
                rsv[qf] = *(const f32x4*)&rs_s[cur][qf * 16 + ksl * 4];
            }
            #pragma unroll
            for (int qf = 0; qf < 4; ++qf)
                #pragma unroll
                for (int cf = 0; cf < 4; ++cf)
                    #pragma unroll
                    for (int j2 = 0; j2 < 4; ++j2)
                        acc[qf][cf][j2] *= rsv[qf][j2];

            // ---- direct-B MFMA: V part (VpT) + T part (f32 coalesced gather) ----
            #pragma unroll
            for (int cf = 0; cf < 4; ++cf) {
                const int col = wave * 64 + cf * 16 + lr;
                const short8 vh = *(const short8*)(VpTh + (size_t)col * 2048 + k0 + kk0);
                const short8 vl = *(const short8*)(VpTl + (size_t)col * 2048 + k0 + kk0);
                float tv[8];
                #pragma unroll
                for (int i = 0; i < 8; ++i)
                    tv[i] = TvT[tk_s[sl][kk0 + i] * 384 + col];
                unsigned int th_[4], tl_[4];
                #pragma unroll
                for (int p = 0; p < 4; ++p) th_[p] = bfpair(tv[2 * p], tv[2 * p + 1], tl_[p]);
                union { uint4v u; short8 s; } cth, ctl;
                cth.u = (uint4v){th_[0], th_[1], th_[2], th_[3]};
                ctl.u = (uint4v){tl_[0], tl_[1], tl_[2], tl_[3]};
                #pragma unroll
                for (int qf = 0; qf < 4; ++qf) {
                    acc[qf][cf] = __builtin_amdgcn_mfma_f32_16x16x32_bf16(pah[qf], vh, acc[qf][cf], 0, 0, 0);
                    acc[qf][cf] = __builtin_amdgcn_mfma_f32_16x16x32_bf16(pah[qf], vl, acc[qf][cf], 0, 0, 0);
                    acc[qf][cf] = __builtin_amdgcn_mfma_f32_16x16x32_bf16(pal[qf], vh, acc[qf][cf], 0, 0, 0);
                    acc[qf][cf] = __builtin_amdgcn_mfma_f32_16x16x32_bf16(pah[qf], cth.s, acc[qf][cf], 0, 0, 0);
                    acc[qf][cf] = __builtin_amdgcn_mfma_f32_16x16x32_bf16(pah[qf], ctl.s, acc[qf][cf], 0, 0, 0);
                    acc[qf][cf] = __builtin_amdgcn_mfma_f32_16x16x32_bf16(pal[qf], cth.s, acc[qf][cf], 0, 0, 0);
                }
            }

            // ---- score(j+1) overlapped in the same region ----
            if (j + 1 < niter) SCORE(j + 1);
            __syncthreads();   // single barrier per iteration
        }

        // ---- epilogue: divide by l, write O ----
        #pragma unroll
        for (int qf = 0; qf < 4; ++qf) {
            f32x4 lv = *(const f32x4*)&l_s[qf * 16 + ksl * 4];
            f32x4 inv;
            #pragma unroll
            for (int j = 0; j < 4; ++j) inv[j] = 1.0f / lv[j];
            #pragma unroll
            for (int j = 0; j < 4; ++j) {
                int row = q0 + qf * 16 + ksl * 4 + j;
                size_t base = ((size_t)b * SEQ + row) * 256 + wave * 64 + lr;
                #pragma unroll
                for (int cf = 0; cf < 4; ++cf)
                    O[base + cf * 16] = acc[qf][cf][j] * inv[j];
            }
        }
    }
}

// ------------------------------------------------------------------
// Stage-2 P3a: split-flash over s. Grid (8, NB), 256 threads.
// PxKVQ: [s][384] (K 0..127, V 128..255, Q 256..383).
// ------------------------------------------------------------------
__global__ __launch_bounds__(256) void s2_p3a(
    const int* __restrict__ tok, const float* __restrict__ q2,
    const float* __restrict__ Tx, const float* __restrict__ PxKVQ,
    const float* __restrict__ O, const float* __restrict__ beta2,
    float* __restrict__ part)
{
    const int b = blockIdx.y, c = blockIdx.x, t = threadIdx.x;
    const int s0 = c * 256;
    const float c2 = beta2[0] * 289.0f;

    __shared__ float q2s[VOC];
    __shared__ int   toks[256];
    __shared__ float es[256];
    __shared__ float red[256];

    if (t < VOC) q2s[t] = q2[b * VOC + t] * c2;
    toks[t] = tok[(size_t)b * SEQ + s0 + t];
    __syncthreads();

    const int s = s0 + t;
    const float* ok = O + ((size_t)b * SEQ + s) * 256;
    const float* xk = Tx + toks[t] * 384;
    const float* pk = PxKVQ + (size_t)s * 384;
    float dot = 0.f;
    #pragma unroll 8
    for (int v = 0; v < VOC; v += 4) {
        f32x4 a = *(const f32x4*)(ok + v);
        f32x4 x = *(const f32x4*)(xk + v);
        f32x4 p = *(const f32x4*)(pk + v);
        f32x4 q = *(const f32x4*)(q2s + v);
        dot += q[0] * (a[0] + x[0] + p[0]) + q[1] * (a[1] + x[1] + p[1])
             + q[2] * (a[2] + x[2] + p[2]) + q[3] * (a[3] + x[3] + p[3]);
    }
    float m = blk_reduce_max(dot, red, t);
    float e = __expf(dot - m);
    es[t] = e;
    float lsum = blk_reduce_sum(e, red, t);

    const int v = t & 127, half = t >> 7;
    float acc = 0.f;
    for (int i = 0; i < 128; ++i) {
        int si = half * 128 + i;
        float ee = es[si];
        acc += ee * (O[((size_t)b * SEQ + s0 + si) * 256 + 128 + v]
                   + Tx[toks[si] * 384 + 128 + v] + PxKVQ[(size_t)(s0 + si) * 384 + 128 + v]);
    }
    red[t] = acc; __syncthreads();
    float* pb = part + ((size_t)b * 8 + c) * 132;
    if (t < VOC) pb[t] = red[t] + red[t + 128];
    if (t == 128) { pb[128] = m; pb[129] = lsum; }
}

// ------------------------------------------------------------------
// Stage-2 P3b: combine 8 partials + logits. Grid (NB), 128 threads.
// ------------------------------------------------------------------
__global__ __launch_bounds__(128) void s2_p3b(
    const float* __restrict__ part, const float* __restrict__ emb,
    const float* __restrict__ beta_out, float* __restrict__ out)
{
    const int b = blockIdx.x, t = threadIdx.x;
    const float co = beta_out[0] * 70.09279563550022f;
    __shared__ float y2[VOC];
    const float* pb = part + (size_t)b * 8 * 132;
    float M = NEG_INF;
    #pragma unroll
    for (int c = 0; c < 8; ++c) M = fmaxf(M, pb[c * 132 + 128]);
    float L = 0.f, y = 0.f;
    #pragma unroll
    for (int c = 0; c < 8; ++c) {
        float sc = __expf(pb[c * 132 + 128] - M);
        L += pb[c * 132 + 129] * sc;
        y += pb[c * 132 + t] * sc;
    }
    y2[t] = y / L;
    __syncthreads();
    float g = 0.f;
    #pragma unroll 8
    for (int v = 0; v < VOC; ++v) g += y2[v] * emb[t * VOC + v];
    out[(size_t)b * VOC + t] = co * g;
}

// ------------------------------------------------------------------
extern "C" void kernel_launch(void* const* d_in, const int* in_sizes, int n_in,
                              void* d_out, int out_size, void* d_ws, size_t ws_size,
                              hipStream_t stream)
{
    const int* tok = (const int*)d_in[0];
    const float* emb = (const float*)d_in[1];
    const float* pos = (const float*)d_in[2];
    const float* WQ1 = (const float*)d_in[3];
    const float* WK1 = (const float*)d_in[4];
    const float* WV1 = (const float*)d_in[5];
    const float* WQ2 = (const float*)d_in[6];
    const float* WK2 = (const float*)d_in[7];
    const float* WV2 = (const float*)d_in[8];
    const float* beta1 = (const float*)d_in[9];
    const float* beta2 = (const float*)d_in[10];
    const float* beta_out = (const float*)d_in[11];
    float* out = (float*)d_out;

    if (ws_size < 178651136ull) return;

    char* wsb = (char*)d_ws;
    #define MB_(x) ((size_t)(x) * 1048576ull)
    // --- O region (128 MB), aliased by all pre-attn split buffers ---
    float* O = (float*)(wsb + MB_(0));
    unsigned short* posH  = (unsigned short*)(wsb + MB_(0));    // [2048][2048] 8 MB
    unsigned short* posL  = (unsigned short*)(wsb + MB_(8));
    unsigned short* WQ1H  = (unsigned short*)(wsb + MB_(16));   // [2176][2048] 8.5 MB
    unsigned short* WQ1L  = (unsigned short*)(wsb + MB_(25));
    unsigned short* WK1H  = (unsigned short*)(wsb + MB_(34));
    unsigned short* WK1L  = (unsigned short*)(wsb + MB_(43));
    unsigned short* WV1H  = (unsigned short*)(wsb + MB_(52));   // [2176][2176] 9.03 MB
    unsigned short* WV1L  = (unsigned short*)(wsb + MB_(62));
    unsigned short* MwTH  = (unsigned short*)(wsb + MB_(72));   // [2176][2176]
    unsigned short* MwTL  = (unsigned short*)(wsb + MB_(82));
    unsigned short* A1H   = (unsigned short*)(wsb + MB_(92));   // [2176][2176]
    unsigned short* A1L   = (unsigned short*)(wsb + MB_(102));
    unsigned short* WV12TH= (unsigned short*)(wsb + MB_(112));  // [384][2176] 1.67 MB
    unsigned short* WV12TL= (unsigned short*)(wsb + MB_(114));
    unsigned short* W2TH  = (unsigned short*)(wsb + MB_(116));  // [384][2176]
    unsigned short* W2TL  = (unsigned short*)(wsb + MB_(118));
    unsigned short* embH  = (unsigned short*)(wsb + MB_(120));  // [128][128] 32 KB
    unsigned short* embL  = (unsigned short*)(wsb + MB_(121));

    // --- persistent region (after O) ---
    float* fp = (float*)(wsb + MB_(128));
    auto take = [&](size_t n) { float* p = fp; fp += n; return p; };
    float* G      = take((size_t)2176 * 2176);
    float* VpKVQ  = take((size_t)2176 * 384);
    float* PxKVQ  = take((size_t)2048 * 384);
    float* Tx     = take((size_t)128 * 384);
    unsigned short* VpTh = (unsigned short*)take((size_t)256 * 2048 / 2);  // [256][2048] bf16
    unsigned short* VpTl = (unsigned short*)take((size_t)256 * 2048 / 2);
    float* q2     = take((size_t)NB * 128);
    float* part   = take((size_t)NB * 8 * 132);

    dim3 blk(256);
    unsigned short* nus = nullptr;
    float* nuf = nullptr;
    GemmDesc dz{};   // zero dummy

    // --- fused splits (plain5 + W2 transpose in one launch) ---
    hipLaunchKernelGGL(split_all, dim3(17440 + 816), blk, 0, stream,
                       pos, posH, posL, 1048576,
                       WQ1, WQ1H, WQ1L, 1114112,
                       WK1, WK1H, WK1L, 1114112,
                       WV1, WV1H, WV1L, 1183744,
                       emb, embH, embL, 4096,
                       17440, WK2, WV2, WQ2, W2TH, W2TL);

    // --- merged GEMMs (quad-descriptor, 3 launches; L3 carries VpT transpose) ---
    // L1: MwT (289) + WV12T (51)
    GemmDesc dMwT   {WK1H, WK1L, WQ1H, WQ1L, nuf, MwTH, MwTL, 2048, 2048, 2176, 2048, 17, 2, 0};
    GemmDesc dWV12T {W2TH, W2TL, WV1H, WV1L, nuf, WV12TH, WV12TL, 2176, 2176, 2176, 2176, 17, 2, 0};
    hipLaunchKernelGGL(gemm_nt_multi4t, dim3(340), blk, 0, stream,
                       dMwT, dWV12T, dz, dz, 289, 340, 340, 340,
                       (const float*)nullptr, 0, 32, 0, nus, nus);

    // L2: A1 (272) + A1e (17) + Vp (48) + Px (48)  [Vp/Px depend only on splits]
    GemmDesc dA1    {posH, posL, MwTH + 128, MwTL + 128, nuf, A1H, A1L, 2048, 2176, 2176, 2048, 17, 2, 0};
    GemmDesc dA1e   {embH, embL, MwTH, MwTL, nuf, A1H + (size_t)2048 * 2176, A1L + (size_t)2048 * 2176,
                     128, 2176, 2176, 128, 17, 2, 0};
    GemmDesc dVp    {posH, posL, WV12TH + 128, WV12TL + 128, VpKVQ, nus, nus, 2048, 2176, 384, 2048, 3, 1, 0};
    GemmDesc dPx    {posH, posL, W2TH + 128, W2TL + 128, PxKVQ, nus, nus, 2048, 2176, 384, 2048, 3, 1, 0};
    hipLaunchKernelGGL(gemm_nt_multi4t, dim3(385), blk, 0, stream,
                       dA1, dA1e, dVp, dPx, 272, 289, 337, 385,
                       (const float*)nullptr, 0, 32, 0, nus, nus);

    // L3: Gtri (152) + Gcol (17) + Vpe (3) + Tx (3) + VpT transpose (512)
    GemmDesc dGtri  {A1H + 128, A1L + 128, posH, posL, G, nus, nus, 2176, 2048, 2176, 2048, 0, 1, 1};
    GemmDesc dGcol  {A1H, A1L, embH, embL, G + 2048, nus, nus, 2176, 128, 2176, 128, 1, 1, 0};
    GemmDesc dVpe   {embH, embL, WV12TH, WV12TL, VpKVQ + (size_t)2048 * 384, nus, nus, 128, 2176, 384, 128, 3, 1, 0};
    GemmDesc dTxd   {embH, embL, W2TH, W2TL, Tx, nus, nus, 128, 2176, 384, 128, 3, 1, 0};
    hipLaunchKernelGGL(gemm_nt_multi4t, dim3(175 + 512), blk, 0, stream,
                       dGtri, dGcol, dVpe, dTxd, 152, 169, 172, 175,
                       VpKVQ, 384, 2048, 256, VpTh, VpTl);

    // --- attention core + fused stage-2 P1/P2 (writes O and q2) ---
    const float* plq = PxKVQ + (size_t)2047 * 384 + 256;
    hipLaunchKernelGGL(attn_mfma, dim3(8, 136), blk, 0, stream,
                       tok, G, VpKVQ, VpTh, VpTl, Tx, plq, beta1, O, q2);

    // --- stage 2 (P3) ---
    hipLaunchKernelGGL(s2_p3a, dim3(8, NB), blk, 0, stream, tok, q2, Tx, PxKVQ, O, beta2, part);
    hipLaunchKernelGGL(s2_p3b, dim3(NB), dim3(128), 0, stream, part, emb, beta_out, out);
}

// Round 27
// 1040.643 us; speedup vs baseline: 1.0150x; 1.0150x over previous
//
#include <hip/hip_runtime.h>
#include <cmath>

#define SEQ 2048
#define NB 64
#define VOC 128
#define DM 2176
#define NEG_INF -1e30f
#define GTLD 132   // padded leading dim for GT: bank = (4q+tk)&31, kills 8-way conflict

typedef __attribute__((ext_vector_type(8))) short short8;
typedef __attribute__((ext_vector_type(4))) float f32x4;
typedef __attribute__((ext_vector_type(4))) unsigned int uint4v;
typedef __attribute__((ext_vector_type(2))) unsigned int uint2v;

// ---------- bf16 split helpers (hi = truncation, lo = remainder) ----------
__device__ __forceinline__ void splitf(float x, unsigned short& h, unsigned short& l) {
    unsigned int u = __float_as_uint(x);
    h = (unsigned short)(u >> 16);
    float d = x - __uint_as_float(u & 0xFFFF0000u);
    l = (unsigned short)(__float_as_uint(d) >> 16);
}
__device__ __forceinline__ unsigned int bfpair(float x0, float x1, unsigned int& lopair) {
    unsigned int u0 = __float_as_uint(x0), u1 = __float_as_uint(x1);
    float d0 = x0 - __uint_as_float(u0 & 0xFFFF0000u);
    float d1 = x1 - __uint_as_float(u1 & 0xFFFF0000u);
    lopair = (__float_as_uint(d0) >> 16) | (__float_as_uint(d1) & 0xFFFF0000u);
    return (u0 >> 16) | (u1 & 0xFFFF0000u);
}

// ------------------------------------------------------------------
// Fused splits: blocks [0, n5) do 5-input plain split (pos, WQ1, WK1,
// WV1, emb; n* in f32x4 units); blocks [n5, n5+816) do the WK2|WV2|WQ2
// split+transpose -> W2T [384][2176] (flattened 68x12 grid).
// ------------------------------------------------------------------
__global__ __launch_bounds__(256) void split_all(
    const float* __restrict__ i0, unsigned short* __restrict__ h0, unsigned short* __restrict__ l0, int n0,
    const float* __restrict__ i1, unsigned short* __restrict__ h1, unsigned short* __restrict__ l1, int n1,
    const float* __restrict__ i2, unsigned short* __restrict__ h2, unsigned short* __restrict__ l2, int n2,
    const float* __restrict__ i3, unsigned short* __restrict__ h3, unsigned short* __restrict__ l3, int n3,
    const float* __restrict__ i4, unsigned short* __restrict__ h4, unsigned short* __restrict__ l4, int n4,
    int n5,
    const float* __restrict__ WK2, const float* __restrict__ WV2,
    const float* __restrict__ WQ2,
    unsigned short* __restrict__ w2h, unsigned short* __restrict__ w2l)
{
    __shared__ float tile[32][33];
    const int t = threadIdx.x;
    if ((int)blockIdx.x >= n5) {
        // ---- splitT3 path ----
        const int id2 = blockIdx.x - n5;
        const int bx = id2 % 68, by = id2 / 68;
        const int src = by >> 2, cblk = by & 3;
        const float* in = (src == 0) ? WK2 : (src == 1) ? WV2 : WQ2;
        const int r0 = bx * 32, c0 = cblk * 32;
        const int x = t & 31, y = t >> 5;
        #pragma unroll
        for (int i = 0; i < 4; ++i) {
            int r = y + i * 8;
            tile[r][x] = in[(size_t)(r0 + r) * 128 + c0 + x];
        }
        __syncthreads();
        #pragma unroll
        for (int i = 0; i < 4; ++i) {
            int c = y + i * 8;
            float v = tile[x][c];
            unsigned short h, l;
            splitf(v, h, l);
            size_t o = (size_t)(src * 128 + c0 + c) * 2176 + r0 + x;
            w2h[o] = h; w2l[o] = l;
        }
        return;
    }
    int i = blockIdx.x * 256 + t;
    const float* in; unsigned short *oh, *ol;
    if (i < n0) { in = i0; oh = h0; ol = l0; }
    else if ((i -= n0) < n1) { in = i1; oh = h1; ol = l1; }
    else if ((i -= n1) < n2) { in = i2; oh = h2; ol = l2; }
    else if ((i -= n2) < n3) { in = i3; oh = h3; ol = l3; }
    else if ((i -= n3) < n4) { in = i4; oh = h4; ol = l4; }
    else return;
    f32x4 v = *(const f32x4*)(in + (size_t)i * 4);
    unsigned int h01, h23, l01, l23;
    h01 = bfpair(v[0], v[1], l01);
    h23 = bfpair(v[2], v[3], l23);
    *(uint2v*)(oh + (size_t)i * 4) = (uint2v){h01, h23};
    *(uint2v*)(ol + (size_t)i * 4) = (uint2v){l01, l23};
}

// ------------------------------------------------------------------
// Quad-descriptor split-bf16 MFMA GEMM (NT), 3-term, plus optional
// trailing transpose region: blocks [nGemmTot, grid) split-transpose
// tsrc[row][0..tNC) (ld tld) -> (th,tl)[c][r] with out ld tNR.
// Tile 128x128, BK=64, 4 waves. mode bit0: f32 C; bit1: split Ch/Cl.
// tri: linear id -> lower-triangle (bm,bn) for bm<16 + full row bm=16.
// ------------------------------------------------------------------
struct GemmDesc {
    const unsigned short *Ah, *Al, *Bh, *Bl;
    float* C; unsigned short *Ch, *Cl;
    int lda, ldb, ldc, K, nx, mode, tri;
};

__global__ __launch_bounds__(256, 2) void gemm_nt_multi4t(
    GemmDesc d0, GemmDesc d1, GemmDesc d2, GemmDesc d3,
    int n0, int n01, int n012, int nGemmTot,
    const float* __restrict__ tsrc, int tld, int tNR, int tNC,
    unsigned short* __restrict__ th, unsigned short* __restrict__ tl)
{
    __shared__ __align__(16) unsigned short sAh[128 * 64], sAl[128 * 64];
    __shared__ __align__(16) unsigned short sBh[128 * 64], sBl[128 * 64];
    const int t = threadIdx.x;
    if ((int)blockIdx.x >= nGemmTot) {
        // ---- transpose path (splitT of tsrc) ----
        float* tile = (float*)sAh;            // 32x33 floats, reuse LDS
        const int id2 = blockIdx.x - nGemmTot;
        const int nbx = tNR >> 5;             // blocks along rows
        const int bx = id2 % nbx, by = id2 / nbx;
        const int r0 = bx * 32, c0 = by * 32;
        const int x = t & 31, y = t >> 5;
        #pragma unroll
        for (int i = 0; i < 4; ++i) {
            int r = y + i * 8;
            tile[r * 33 + x] = tsrc[(size_t)(r0 + r) * tld + c0 + x];
        }
        __syncthreads();
        #pragma unroll
        for (int i = 0; i < 4; ++i) {
            int c = y + i * 8;
            float v = tile[x * 33 + c];
            unsigned short h, l;
            splitf(v, h, l);
            size_t o = (size_t)(c0 + c) * tNR + r0 + x;
            th[o] = h; tl[o] = l;
        }
        return;
    }
    GemmDesc d;
    int id = blockIdx.x;
    if (id < n0) d = d0;
    else if (id < n01) { d = d1; id -= n0; }
    else if (id < n012) { d = d2; id -= n01; }
    else { d = d3; id -= n012; }
    int bmi, bni;
    if (d.tri) {
        if (id < 136) {
            int bm_ = (int)((sqrtf(8.f * id + 1.f) - 1.f) * 0.5f);
            while ((bm_ + 1) * (bm_ + 2) / 2 <= id) ++bm_;
            while (bm_ * (bm_ + 1) / 2 > id) --bm_;
            bmi = bm_; bni = id - bm_ * (bm_ + 1) / 2;
        } else { bmi = 16; bni = id - 136; }
    } else { bmi = id / d.nx; bni = id % d.nx; }
    const int bm = bmi * 128, bn = bni * 128;
    const int lane = t & 63, wave = t >> 6;
    const int wr = wave >> 1, wc = wave & 1;
    const int lr = lane & 15;

    f32x4 acc[4][4];
    #pragma unroll
    for (int i = 0; i < 4; ++i)
        #pragma unroll
        for (int j = 0; j < 4; ++j) acc[i][j] = (f32x4){0.f, 0.f, 0.f, 0.f};

    for (int k0 = 0; k0 < d.K; k0 += 64) {
        __syncthreads();
        #pragma unroll
        for (int i = 0; i < 4; ++i) {
            int idx = t + i * 256;
            int r = idx >> 3, kc = (idx & 7) * 8;
            int off = (r * 128 + kc * 2) ^ ((r & 7) << 4);
            size_t ga = (size_t)(bm + r) * d.lda + k0 + kc;
            size_t gb = (size_t)(bn + r) * d.ldb + k0 + kc;
            *(short8*)((char*)sAh + off) = *(const short8*)(d.Ah + ga);
            *(short8*)((char*)sAl + off) = *(const short8*)(d.Al + ga);
            *(short8*)((char*)sBh + off) = *(const short8*)(d.Bh + gb);
            *(short8*)((char*)sBl + off) = *(const short8*)(d.Bl + gb);
        }
        __syncthreads();
        #pragma unroll
        for (int ks = 0; ks < 2; ++ks) {
            const int kby = ks * 64 + ((lane >> 4) << 4);
            short8 ah[4], al[4];
            #pragma unroll
            for (int rf = 0; rf < 4; ++rf) {
                int row = wr * 64 + rf * 16 + lr;
                int off = (row * 128 + kby) ^ ((row & 7) << 4);
                ah[rf] = *(const short8*)((const char*)sAh + off);
                al[rf] = *(const short8*)((const char*)sAl + off);
            }
            #pragma unroll
            for (int cf = 0; cf < 4; ++cf) {
                int col = wc * 64 + cf * 16 + lr;
                int off = (col * 128 + kby) ^ ((col & 7) << 4);
                short8 bh = *(const short8*)((const char*)sBh + off);
                short8 bl = *(const short8*)((const char*)sBl + off);
                #pragma unroll
                for (int rf = 0; rf < 4; ++rf) {
                    acc[rf][cf] = __builtin_amdgcn_mfma_f32_16x16x32_bf16(ah[rf], bh, acc[rf][cf], 0, 0, 0);
                    acc[rf][cf] = __builtin_amdgcn_mfma_f32_16x16x32_bf16(ah[rf], bl, acc[rf][cf], 0, 0, 0);
                    acc[rf][cf] = __builtin_amdgcn_mfma_f32_16x16x32_bf16(al[rf], bh, acc[rf][cf], 0, 0, 0);
                }
            }
        }
    }
    #pragma unroll
    for (int rf = 0; rf < 4; ++rf) {
        #pragma unroll
        for (int j = 0; j < 4; ++j) {
            int row = bm + wr * 64 + rf * 16 + ((lane >> 4) << 2) + j;
            #pragma unroll
            for (int cf = 0; cf < 4; ++cf) {
                int col = bn + wc * 64 + cf * 16 + lr;
                float v = acc[rf][cf][j];
                size_t o = (size_t)row * d.ldc + col;
                if (d.mode & 1) d.C[o] = v;
                if (d.mode & 2) { unsigned short h, l; splitf(v, h, l); d.Ch[o] = h; d.Cl[o] = l; }
            }
        }
    }
}

// ------------------------------------------------------------------
// block reduce helpers
// ------------------------------------------------------------------
__device__ __forceinline__ float blk_reduce_max(float v, float* red, int t)
{
    red[t] = v; __syncthreads();
    #pragma unroll
    for (int s = 128; s >= 1; s >>= 1) {
        if (t < s) red[t] = fmaxf(red[t], red[t + s]);
        __syncthreads();
    }
    float r = red[0]; __syncthreads(); return r;
}
__device__ __forceinline__ float blk_reduce_sum(float v, float* red, int t)
{
    red[t] = v; __syncthreads();
    #pragma unroll
    for (int s = 128; s >= 1; s >>= 1) {
        if (t < s) red[t] += red[t + s];
        __syncthreads();
    }
    float r = red[0]; __syncthreads(); return r;
}

// ------------------------------------------------------------------
// MFMA attention core, v11 (R25-proven best): v10 single-barrier overlap
// + GT leading-dim pad 128 -> 132 (score gather bank = (4q+tk)&31; the
// 8 lanes sharing a token had different q, same bank -> 8-way conflict;
// now 8 distinct banks). P1/P2 blocks dispatched LAST (y >= 128) —
// front-dispatch polluted L2 during the attn ramp (R26: +13 µs).
// Grid (8, 136), 256 threads:
//   y < 128 : attention. b = y>>1, sel = y&1.
//             sel 0 -> q-tiles {x, 31-x}; sel 1 -> {15-x, 16+x} (66 iters).
//             gridDim.x = 8 keeps linear%8 == x -> XCD-local G.
//   y >= 128: merged stage-2 P1+P2 for batch (y-128)*8+x -> writes q2.
// ------------------------------------------------------------------
__global__ __launch_bounds__(256, 3) void attn_mfma(
    const int* __restrict__ tok,
    const float* __restrict__ G,
    const float* __restrict__ VpKVQ,
    const unsigned short* __restrict__ VpTh, const unsigned short* __restrict__ VpTl,
    const float* __restrict__ Tx, const float* __restrict__ plq,
    const float* __restrict__ beta1,
    float* __restrict__ O, float* __restrict__ q2)
{
    const int t = threadIdx.x;
    const int lane = t & 63, wave = t >> 6;
    const float c1 = beta1[0] * 1.12890625f;

    __shared__ __align__(16) unsigned short Ph[2][64 * 32], Pl[2][64 * 32];
    __shared__ float GT[64 * GTLD];
    __shared__ float m_s[64], l_s[64], rs_s[2][64];
    __shared__ int tq_s[64], tk_s[3][32];

    if (blockIdx.y >= 128) {
        // ======== merged stage-2 P1+P2 for batch bb ========
        const int bb = (blockIdx.y - 128) * 8 + blockIdx.x;
        float* a_s = GT;              // [2048]
        float* red_s = GT + 2048;     // [256]
        float* w_s = GT + 2048 + 256; // [128]
        const int* tokb = tok + (size_t)bb * SEQ;
        const int tq = tokb[SEQ - 1];
        const float* Grow_q = G + (size_t)(SEQ - 1) * 2176;
        const float* Grow_t = G + (size_t)(2048 + tq) * 2176;

        float lmax = NEG_INF;
        for (int i = t; i < SEQ; i += 256) {
            int tk = tokb[i];
            float s = c1 * (Grow_t[2048 + tk] + Grow_t[i] + Grow_q[2048 + tk] + Grow_q[i]);
            a_s[i] = s;
            lmax = fmaxf(lmax, s);
        }
        float m = blk_reduce_max(lmax, red_s, t);
        float lsum = 0.f;
        for (int i = t; i < SEQ; i += 256) {
            float e = __expf(a_s[i] - m);
            a_s[i] = e;
            lsum += e;
        }
        float l = blk_reduce_sum(lsum, red_s, t);
        float inv = 1.f / l;
        if (t < VOC) w_s[t] = 0.f;
        __syncthreads();
        for (int i = t; i < SEQ; i += 256) {
            float a = a_s[i] * inv;
            a_s[i] = a;
            atomicAdd(&w_s[tokb[i]], a);
        }
        __syncthreads();
        // ---- P2: q2[bb][v] ----
        const int v = t & 127, half = t >> 7;
        float acc = 0.f;
        for (int i = 0; i < 1024; ++i) {
            int s = half * 1024 + i;
            acc += a_s[s] * VpKVQ[(size_t)s * 384 + 256 + v];
        }
        if (half == 0) {
            for (int tt = 0; tt < VOC; ++tt)
                acc += w_s[tt] * VpKVQ[(size_t)(2048 + tt) * 384 + 256 + v];
        }
        red_s[t] = acc; __syncthreads();
        if (t < VOC)
            q2[bb * VOC + t] = red_s[t] + red_s[t + 128] + Tx[tq * 384 + 256 + t] + plq[t];
        return;
    }

    // ======== attention path ========
    const int b = blockIdx.y >> 1;
    const int sel = blockIdx.y & 1;
    const int grp = blockIdx.x;      // 0..7, == XCD under linear round-robin

    const int qr = t >> 3;           // 0..31
    const int kb4 = (t & 7) * 4;     // 0..28
    const int lr = lane & 15;
    const int ksl = lane >> 4;       // 0..3
    const int kk0 = ksl * 8;
    const float* TvT = VpKVQ + (size_t)2048 * 384;   // token rows [128][384]

    const int qts[2] = {sel ? (15 - grp) : grp, sel ? (16 + grp) : (31 - grp)};

    for (int pass = 0; pass < 2; ++pass) {
        const int qt = qts[pass];
        const int q0 = qt * 64;
        const int niter = 2 * qt + 2;

        __syncthreads();                 // previous pass fully done
        if (t < 64) {
            tq_s[t] = tok[(size_t)b * SEQ + q0 + t];
            m_s[t] = NEG_INF;
            l_s[t] = 0.f;
        }
        __syncthreads();                 // tq_s visible
        // ---- GT[q][tk] = Gqt + Gtt (one coalesced pass) ----
        {
            const int c4 = (t & 31) * 4;
            #pragma unroll
            for (int i = 0; i < 8; ++i) {
                int q = (t >> 5) + i * 8;
                f32x4 a = *(const f32x4*)&G[(size_t)(q0 + q) * 2176 + 2048 + c4];
                f32x4 g = *(const f32x4*)&G[(size_t)(2048 + tq_s[q]) * 2176 + 2048 + c4];
                *(f32x4*)&GT[q * GTLD + c4] = a + g;
            }
        }
        // prologue: tokens tile0 -> slot 0, G rows tile0 -> regs
        if (t < 32) tk_s[0][t] = tok[(size_t)b * SEQ + t];
        f32x4 gqk_c[2], gtk_c[2];
        #pragma unroll
        for (int rr = 0; rr < 2; ++rr) {
            int q = qr + rr * 32;
            gqk_c[rr] = *(const f32x4*)&G[(size_t)(q0 + q) * 2176 + kb4];
            gtk_c[rr] = *(const f32x4*)&G[(size_t)(2048 + tq_s[q]) * 2176 + kb4];
        }

        f32x4 acc[4][4];
        #pragma unroll
        for (int i = 0; i < 4; ++i)
            #pragma unroll
            for (int j = 0; j < 4; ++j) acc[i][j] = (f32x4){0.f, 0.f, 0.f, 0.f};

        // SCORE(i): uses gqk_c/gtk_c (tile i), tk_s[i%3]; writes P[i&1],
        // rs_s[i&1]; prefetches tokens(i+1) -> slot (i+1)%3.
        auto SCORE = [&](int i) {
            const int k0s = i * 32;
            const int cs = i & 1;
            const int sl = i % 3;
            unsigned short* PhC = Ph[cs];
            unsigned short* PlC = Pl[cs];
            const int k0p = (i + 1 < niter) ? k0s + 32 : k0s;
            if (t < 32) tk_s[(i + 1) % 3][t] = tok[(size_t)b * SEQ + k0p + t];
            #pragma unroll
            for (int rr = 0; rr < 2; ++rr) {
                const int q = qr + rr * 32;
                const int qg = q0 + q;
                float s[4];
                #pragma unroll
                for (int j = 0; j < 4; ++j) {
                    int kg = k0s + kb4 + j;
                    s[j] = (kg <= qg)
                         ? c1 * (gqk_c[rr][j] + gtk_c[rr][j] + GT[q * GTLD + tk_s[sl][kb4 + j]])
                         : NEG_INF;
                }
                float tmax = fmaxf(fmaxf(s[0], s[1]), fmaxf(s[2], s[3]));
                tmax = fmaxf(tmax, __shfl_xor(tmax, 1));
                tmax = fmaxf(tmax, __shfl_xor(tmax, 2));
                tmax = fmaxf(tmax, __shfl_xor(tmax, 4));
                const float m_old = m_s[q];
                const float mnew = fmaxf(m_old, tmax);
                float p0 = __expf(s[0] - mnew), p1 = __expf(s[1] - mnew);
                float p2 = __expf(s[2] - mnew), p3 = __expf(s[3] - mnew);
                float lsum = p0 + p1 + p2 + p3;
                lsum += __shfl_xor(lsum, 1);
                lsum += __shfl_xor(lsum, 2);
                lsum += __shfl_xor(lsum, 4);
                unsigned int l01, l23;
                unsigned int h01 = bfpair(p0, p1, l01);
                unsigned int h23 = bfpair(p2, p3, l23);
                int i16 = q * 4 + (((kb4 >> 3) + (q >> 1)) & 3);
                int pbyte = i16 * 16 + ((kb4 & 4) << 1);
                *(uint2v*)((char*)PhC + pbyte) = (uint2v){h01, h23};
                *(uint2v*)((char*)PlC + pbyte) = (uint2v){l01, l23};
                if ((t & 7) == 0) {
                    float rs = __expf(m_old - mnew);
                    m_s[q] = mnew;
                    l_s[q] = l_s[q] * rs + lsum;
                    rs_s[cs][q] = rs;
                }
            }
        };

        // ---- score(0) ----
        __syncthreads();                 // GT + tk slot0 visible
        SCORE(0);
        __syncthreads();                 // barrier 0: P[0]/rs[0] visible

        for (int j = 0; j < niter; ++j) {
            const int cur = j & 1;
            const int sl = j % 3;
            const int k0 = j * 32;

            // ---- G-row prefetch for score(j+1) (regs; hides under PV) ----
            const int k0n = (j + 1 < niter) ? k0 + 32 : k0;
            #pragma unroll
            for (int rr = 0; rr < 2; ++rr) {
                int q = qr + rr * 32;
                gqk_c[rr] = *(const f32x4*)&G[(size_t)(q0 + q) * 2176 + k0n + kb4];
                gtk_c[rr] = *(const f32x4*)&G[(size_t)(2048 + tq_s[q]) * 2176 + k0n + kb4];
            }

            // ---- P frags + rescale ----
            const unsigned short* PhC = Ph[cur];
            const unsigned short* PlC = Pl[cur];
            short8 pah[4], pal[4];
            f32x4 rsv[4];
            #pragma unroll
            for (int qf = 0; qf < 4; ++qf) {
                int row = qf * 16 + lr;
                int i16 = row * 4 + ((ksl + (row >> 1)) & 3);
                pah[qf] = *(const short8*)((const char*)PhC + i16 * 16);
                pal[qf] = *(const short8*)((const char*)PlC + i16 * 16);
                rsv[qf] = *(const f32x4*)&rs_s[cur][qf * 16 + ksl * 4];
            }
            #pragma unroll
            for (int qf = 0; qf < 4; ++qf)
                #pragma unroll
                for (int cf = 0; cf < 4; ++cf)
                    #pragma unroll
                    for (int j2 = 0; j2 < 4; ++j2)
                        acc[qf][cf][j2] *= rsv[qf][j2];

            // ---- direct-B MFMA: V part (VpT) + T part (f32 coalesced gather) ----
            #pragma unroll
            for (int cf = 0; cf < 4; ++cf) {
                const int col = wave * 64 + cf * 16 + lr;
                const short8 vh = *(const short8*)(VpTh + (size_t)col * 2048 + k0 + kk0);
                const short8 vl = *(const short8*)(VpTl + (size_t)col * 2048 + k0 + kk0);
                float tv[8];
                #pragma unroll
                for (int i = 0; i < 8; ++i)
                    tv[i] = TvT[tk_s[sl][kk0 + i] * 384 + col];
                unsigned int th_[4], tl_[4];
                #pragma unroll
                for (int p = 0; p < 4; ++p) th_[p] = bfpair(tv[2 * p], tv[2 * p + 1], tl_[p]);
                union { uint4v u; short8 s; } cth, ctl;
                cth.u = (uint4v){th_[0], th_[1], th_[2], th_[3]};
                ctl.u = (uint4v){tl_[0], tl_[1], tl_[2], tl_[3]};
                #pragma unroll
                for (int qf = 0; qf < 4; ++qf) {
                    acc[qf][cf] = __builtin_amdgcn_mfma_f32_16x16x32_bf16(pah[qf], vh, acc[qf][cf], 0, 0, 0);
                    acc[qf][cf] = __builtin_amdgcn_mfma_f32_16x16x32_bf16(pah[qf], vl, acc[qf][cf], 0, 0, 0);
                    acc[qf][cf] = __builtin_amdgcn_mfma_f32_16x16x32_bf16(pal[qf], vh, acc[qf][cf], 0, 0, 0);
                    acc[qf][cf] = __builtin_amdgcn_mfma_f32_16x16x32_bf16(pah[qf], cth.s, acc[qf][cf], 0, 0, 0);
                    acc[qf][cf] = __builtin_amdgcn_mfma_f32_16x16x32_bf16(pah[qf], ctl.s, acc[qf][cf], 0, 0, 0);
                    acc[qf][cf] = __builtin_amdgcn_mfma_f32_16x16x32_bf16(pal[qf], cth.s, acc[qf][cf], 0, 0, 0);
                }
            }

            // ---- score(j+1) overlapped in the same region ----
            if (j + 1 < niter) SCORE(j + 1);
            __syncthreads();   // single barrier per iteration
        }

        // ---- epilogue: divide by l, write O ----
        #pragma unroll
        for (int qf = 0; qf < 4; ++qf) {
            f32x4 lv = *(const f32x4*)&l_s[qf * 16 + ksl * 4];
            f32x4 inv;
            #pragma unroll
            for (int j = 0; j < 4; ++j) inv[j] = 1.0f / lv[j];
            #pragma unroll
            for (int j = 0; j < 4; ++j) {
                int row = q0 + qf * 16 + ksl * 4 + j;
                size_t base = ((size_t)b * SEQ + row) * 256 + wave * 64 + lr;
                #pragma unroll
                for (int cf = 0; cf < 4; ++cf)
                    O[base + cf * 16] = acc[qf][cf][j] * inv[j];
            }
        }
    }
}

// ------------------------------------------------------------------
// Stage-2 P3a: split-flash over s. Grid (8, NB), 256 threads.
// PxKVQ: [s][384] (K 0..127, V 128..255, Q 256..383).
// ------------------------------------------------------------------
__global__ __launch_bounds__(256) void s2_p3a(
    const int* __restrict__ tok, const float* __restrict__ q2,
    const float* __restrict__ Tx, const float* __restrict__ PxKVQ,
    const float* __restrict__ O, const float* __restrict__ beta2,
    float* __restrict__ part)
{
    const int b = blockIdx.y, c = blockIdx.x, t = threadIdx.x;
    const int s0 = c * 256;
    const float c2 = beta2[0] * 289.0f;

    __shared__ float q2s[VOC];
    __shared__ int   toks[256];
    __shared__ float es[256];
    __shared__ float red[256];

    if (t < VOC) q2s[t] = q2[b * VOC + t] * c2;
    toks[t] = tok[(size_t)b * SEQ + s0 + t];
    __syncthreads();

    const int s = s0 + t;
    const float* ok = O + ((size_t)b * SEQ + s) * 256;
    const float* xk = Tx + toks[t] * 384;
    const float* pk = PxKVQ + (size_t)s * 384;
    float dot = 0.f;
    #pragma unroll 8
    for (int v = 0; v < VOC; v += 4) {
        f32x4 a = *(const f32x4*)(ok + v);
        f32x4 x = *(const f32x4*)(xk + v);
        f32x4 p = *(const f32x4*)(pk + v);
        f32x4 q = *(const f32x4*)(q2s + v);
        dot += q[0] * (a[0] + x[0] + p[0]) + q[1] * (a[1] + x[1] + p[1])
             + q[2] * (a[2] + x[2] + p[2]) + q[3] * (a[3] + x[3] + p[3]);
    }
    float m = blk_reduce_max(dot, red, t);
    float e = __expf(dot - m);
    es[t] = e;
    float lsum = blk_reduce_sum(e, red, t);

    const int v = t & 127, half = t >> 7;
    float acc = 0.f;
    for (int i = 0; i < 128; ++i) {
        int si = half * 128 + i;
        float ee = es[si];
        acc += ee * (O[((size_t)b * SEQ + s0 + si) * 256 + 128 + v]
                   + Tx[toks[si] * 384 + 128 + v] + PxKVQ[(size_t)(s0 + si) * 384 + 128 + v]);
    }
    red[t] = acc; __syncthreads();
    float* pb = part + ((size_t)b * 8 + c) * 132;
    if (t < VOC) pb[t] = red[t] + red[t + 128];
    if (t == 128) { pb[128] = m; pb[129] = lsum; }
}

// ------------------------------------------------------------------
// Stage-2 P3b: combine 8 partials + logits. Grid (NB), 128 threads.
// ------------------------------------------------------------------
__global__ __launch_bounds__(128) void s2_p3b(
    const float* __restrict__ part, const float* __restrict__ emb,
    const float* __restrict__ beta_out, float* __restrict__ out)
{
    const int b = blockIdx.x, t = threadIdx.x;
    const float co = beta_out[0] * 70.09279563550022f;
    __shared__ float y2[VOC];
    const float* pb = part + (size_t)b * 8 * 132;
    float M = NEG_INF;
    #pragma unroll
    for (int c = 0; c < 8; ++c) M = fmaxf(M, pb[c * 132 + 128]);
    float L = 0.f, y = 0.f;
    #pragma unroll
    for (int c = 0; c < 8; ++c) {
        float sc = __expf(pb[c * 132 + 128] - M);
        L += pb[c * 132 + 129] * sc;
        y += pb[c * 132 + t] * sc;
    }
    y2[t] = y / L;
    __syncthreads();
    float g = 0.f;
    #pragma unroll 8
    for (int v = 0; v < VOC; ++v) g += y2[v] * emb[t * VOC + v];
    out[(size_t)b * VOC + t] = co * g;
}

// ------------------------------------------------------------------
extern "C" void kernel_launch(void* const* d_in, const int* in_sizes, int n_in,
                              void* d_out, int out_size, void* d_ws, size_t ws_size,
                              hipStream_t stream)
{
    const int* tok = (const int*)d_in[0];
    const float* emb = (const float*)d_in[1];
    const float* pos = (const float*)d_in[2];
    const float* WQ1 = (const float*)d_in[3];
    const float* WK1 = (const float*)d_in[4];
    const float* WV1 = (const float*)d_in[5];
    const float* WQ2 = (const float*)d_in[6];
    const float* WK2 = (const float*)d_in[7];
    const float* WV2 = (const float*)d_in[8];
    const float* beta1 = (const float*)d_in[9];
    const float* beta2 = (const float*)d_in[10];
    const float* beta_out = (const float*)d_in[11];
    float* out = (float*)d_out;

    if (ws_size < 178651136ull) return;

    char* wsb = (char*)d_ws;
    #define MB_(x) ((size_t)(x) * 1048576ull)
    // --- O region (128 MB), aliased by all pre-attn split buffers ---
    float* O = (float*)(wsb + MB_(0));
    unsigned short* posH  = (unsigned short*)(wsb + MB_(0));    // [2048][2048] 8 MB
    unsigned short* posL  = (unsigned short*)(wsb + MB_(8));
    unsigned short* WQ1H  = (unsigned short*)(wsb + MB_(16));   // [2176][2048] 8.5 MB
    unsigned short* WQ1L  = (unsigned short*)(wsb + MB_(25));
    unsigned short* WK1H  = (unsigned short*)(wsb + MB_(34));
    unsigned short* WK1L  = (unsigned short*)(wsb + MB_(43));
    unsigned short* WV1H  = (unsigned short*)(wsb + MB_(52));   // [2176][2176] 9.03 MB
    unsigned short* WV1L  = (unsigned short*)(wsb + MB_(62));
    unsigned short* MwTH  = (unsigned short*)(wsb + MB_(72));   // [2176][2176]
    unsigned short* MwTL  = (unsigned short*)(wsb + MB_(82));
    unsigned short* A1H   = (unsigned short*)(wsb + MB_(92));   // [2176][2176]
    unsigned short* A1L   = (unsigned short*)(wsb + MB_(102));
    unsigned short* WV12TH= (unsigned short*)(wsb + MB_(112));  // [384][2176] 1.67 MB
    unsigned short* WV12TL= (unsigned short*)(wsb + MB_(114));
    unsigned short* W2TH  = (unsigned short*)(wsb + MB_(116));  // [384][2176]
    unsigned short* W2TL  = (unsigned short*)(wsb + MB_(118));
    unsigned short* embH  = (unsigned short*)(wsb + MB_(120));  // [128][128] 32 KB
    unsigned short* embL  = (unsigned short*)(wsb + MB_(121));

    // --- persistent region (after O) ---
    float* fp = (float*)(wsb + MB_(128));
    auto take = [&](size_t n) { float* p = fp; fp += n; return p; };
    float* G      = take((size_t)2176 * 2176);
    float* VpKVQ  = take((size_t)2176 * 384);
    float* PxKVQ  = take((size_t)2048 * 384);
    float* Tx     = take((size_t)128 * 384);
    unsigned short* VpTh = (unsigned short*)take((size_t)256 * 2048 / 2);  // [256][2048] bf16
    unsigned short* VpTl = (unsigned short*)take((size_t)256 * 2048 / 2);
    float* q2     = take((size_t)NB * 128);
    float* part   = take((size_t)NB * 8 * 132);

    dim3 blk(256);
    unsigned short* nus = nullptr;
    float* nuf = nullptr;
    GemmDesc dz{};   // zero dummy

    // --- fused splits (plain5 + W2 transpose in one launch) ---
    hipLaunchKernelGGL(split_all, dim3(17440 + 816), blk, 0, stream,
                       pos, posH, posL, 1048576,
                       WQ1, WQ1H, WQ1L, 1114112,
                       WK1, WK1H, WK1L, 1114112,
                       WV1, WV1H, WV1L, 1183744,
                       emb, embH, embL, 4096,
                       17440, WK2, WV2, WQ2, W2TH, W2TL);

    // --- merged GEMMs (quad-descriptor, 3 launches; L3 carries VpT transpose) ---
    // L1: MwT (289) + WV12T (51)
    GemmDesc dMwT   {WK1H, WK1L, WQ1H, WQ1L, nuf, MwTH, MwTL, 2048, 2048, 2176, 2048, 17, 2, 0};
    GemmDesc dWV12T {W2TH, W2TL, WV1H, WV1L, nuf, WV12TH, WV12TL, 2176, 2176, 2176, 2176, 17, 2, 0};
    hipLaunchKernelGGL(gemm_nt_multi4t, dim3(340), blk, 0, stream,
                       dMwT, dWV12T, dz, dz, 289, 340, 340, 340,
                       (const float*)nullptr, 0, 32, 0, nus, nus);

    // L2: A1 (272) + A1e (17) + Vp (48) + Px (48)  [Vp/Px depend only on splits]
    GemmDesc dA1    {posH, posL, MwTH + 128, MwTL + 128, nuf, A1H, A1L, 2048, 2176, 2176, 2048, 17, 2, 0};
    GemmDesc dA1e   {embH, embL, MwTH, MwTL, nuf, A1H + (size_t)2048 * 2176, A1L + (size_t)2048 * 2176,
                     128, 2176, 2176, 128, 17, 2, 0};
    GemmDesc dVp    {posH, posL, WV12TH + 128, WV12TL + 128, VpKVQ, nus, nus, 2048, 2176, 384, 2048, 3, 1, 0};
    GemmDesc dPx    {posH, posL, W2TH + 128, W2TL + 128, PxKVQ, nus, nus, 2048, 2176, 384, 2048, 3, 1, 0};
    hipLaunchKernelGGL(gemm_nt_multi4t, dim3(385), blk, 0, stream,
                       dA1, dA1e, dVp, dPx, 272, 289, 337, 385,
                       (const float*)nullptr, 0, 32, 0, nus, nus);

    // L3: Gtri (152) + Gcol (17) + Vpe (3) + Tx (3) + VpT transpose (512)
    GemmDesc dGtri  {A1H + 128, A1L + 128, posH, posL, G, nus, nus, 2176, 2048, 2176, 2048, 0, 1, 1};
    GemmDesc dGcol  {A1H, A1L, embH, embL, G + 2048, nus, nus, 2176, 128, 2176, 128, 1, 1, 0};
    GemmDesc dVpe   {embH, embL, WV12TH, WV12TL, VpKVQ + (size_t)2048 * 384, nus, nus, 128, 2176, 384, 128, 3, 1, 0};
    GemmDesc dTxd   {embH, embL, W2TH, W2TL, Tx, nus, nus, 128, 2176, 384, 128, 3, 1, 0};
    hipLaunchKernelGGL(gemm_nt_multi4t, dim3(175 + 512), blk, 0, stream,
                       dGtri, dGcol, dVpe, dTxd, 152, 169, 172, 175,
                       VpKVQ, 384, 2048, 256, VpTh, VpTl);

    // --- attention core + fused stage-2 P1/P2 (writes O and q2) ---
    const float* plq = PxKVQ + (size_t)2047 * 384 + 256;
    hipLaunchKernelGGL(attn_mfma, dim3(8, 136), blk, 0, stream,
                       tok, G, VpKVQ, VpTh, VpTl, Tx, plq, beta1, O, q2);

    // --- stage 2 (P3) ---
    hipLaunchKernelGGL(s2_p3a, dim3(8, NB), blk, 0, stream, tok, q2, Tx, PxKVQ, O, beta2, part);
    hipLaunchKernelGGL(s2_p3b, dim3(NB), dim3(128), 0, stream, part, emb, beta_out, out);
}